// Round 14
// baseline (53.951 us; speedup 1.0000x reference)
//
#include <hip/hip_runtime.h>
#include <stdint.h>
#include <math.h>

#define NB 8
#define NC 3
#define HG 256
#define WG 256
#define IMG 1024
#define TOPK 256
#define HALF 32
#define PEAK_THRESH 0.95f
#define NEGV (-1e30f)
#define SELCAP 2048        // selected-set capacity (expected nsel ~290)
#define VB_LO 0x3F733334u  // smallest float bits > 0.95f
// value range (0.95,1) spans 0xCCCCC = 838,860 ULPs; >>12 -> ~205 live buckets of 256
#define NBUCK 256
#define BSHIFT 12

#define ROWS_PB 16                 // rows per peaks block
#define GRPS (HG / ROWS_PB)        // 16 row-groups per plane
#define PLANES (NB * NC)           // 24
#define PK_BLOCKS (PLANES * GRPS)  // 384
#define SLOTS 256                  // candidate slots per peaks block (mean ~118)

typedef float f32x4 __attribute__((ext_vector_type(4)));

// ws layout (bytes):
//   [0, 1536)                      : uint32 bcnt[PK_BLOCKS]
//   [4096, 4096+PK_BLOCKS*SLOTS*8) : uint64 bcand[PK_BLOCKS][SLOTS]   (786 KB)
//   then                           : int4 sel[NB*TOPK]   {y1, x1, valid, 0}
//   then                           : uint32 order[NB*TOPK] (spatial slot -> value rank)
#define WS_BCAND_OFF 4096
#define WS_SEL_OFF   (WS_BCAND_OFF + (size_t)PK_BLOCKS * SLOTS * 8)
#define WS_ORD_OFF   (WS_SEL_OFF + (size_t)NB * TOPK * 16)

// ---------------- Kernel 1: 16-row-tile separable 5x5 peak NMS, slot compaction ----------------
__global__ void __launch_bounds__(256) peaks_kernel(const float* __restrict__ g,
                                                    float* __restrict__ peaks_out,
                                                    uint32_t* __restrict__ bcnt,
                                                    unsigned long long* __restrict__ bcand) {
    __shared__ float vms[ROWS_PB][WG];
    __shared__ unsigned long long lkeys[SLOTS];
    __shared__ uint32_t lcount;

    int blk   = blockIdx.x;
    int grp   = blk & (GRPS - 1);
    int plane = blk >> 4;              // b*NC + c
    int c     = plane % NC;
    int y0    = grp * ROWS_PB;
    int x     = threadIdx.x;

    if (x == 0) lcount = 0;

    const float* gc = g + (size_t)plane * (HG * WG);
    float col[ROWS_PB + 4];
#pragma unroll
    for (int d = 0; d < ROWS_PB + 4; ++d) {
        int yy = y0 - 2 + d;
        col[d] = (yy >= 0 && yy < HG) ? gc[yy * WG + x] : -INFINITY;
    }
#pragma unroll
    for (int r = 0; r < ROWS_PB; ++r)
        vms[r][x] = fmaxf(fmaxf(fmaxf(col[r], col[r + 1]), fmaxf(col[r + 2], col[r + 3])),
                          col[r + 4]);
    __syncthreads();                   // also orders lcount=0 before LDS atomics

#pragma unroll
    for (int r = 0; r < ROWS_PB; ++r) {
        float v = col[r + 2];
        float h = vms[r][x];
        if (x >= 2)      h = fmaxf(h, vms[r][x - 2]);
        if (x >= 1)      h = fmaxf(h, vms[r][x - 1]);
        if (x <= WG - 2) h = fmaxf(h, vms[r][x + 1]);
        if (x <= WG - 3) h = fmaxf(h, vms[r][x + 2]);
        bool peak = (h == v) && (v > PEAK_THRESH);
        peaks_out[(size_t)plane * (HG * WG) + (y0 + r) * WG + x] = peak ? v : 0.0f;
        if (peak) {
            uint32_t pos = atomicAdd(&lcount, 1u);
            if (pos < SLOTS) {
                int cell = c * (HG * WG) + (y0 + r) * WG + x;
                lkeys[pos] = ((unsigned long long)__float_as_uint(v) << 32) |
                             (uint32_t)(~(uint32_t)cell);
            }
        }
    }
    __syncthreads();
    uint32_t n = min(lcount, (uint32_t)SLOTS);
    if (x == 0) bcnt[blk] = n;
    if ((uint32_t)x < n) bcand[(size_t)blk * SLOTS + x] = lkeys[x];
}

// ---------------- Kernel 2: histogram-select + rank-by-count top-256 + spatial order ----------------
__device__ __forceinline__ void emit_entry(int b, int kk, int idx, int vld,
                                           float* boxes_out, float* valid_out, int4* sel) {
    int rem = idx & 65535;
    int cy = rem >> 8, cx = rem & 255;
    int x1 = cx - HALF, y1 = cy - HALF;
    float4 bo = make_float4((float)x1, (float)y1, (float)(cx + HALF), (float)(cy + HALF));
    *(float4*)(boxes_out + ((size_t)b * TOPK + kk) * 4) = bo;
    valid_out[b * TOPK + kk] = vld ? 1.0f : 0.0f;
    sel[b * TOPK + kk] = make_int4(y1, x1, vld, 0);
}

#define BLKS_PER_IMG (NC * GRPS)   // 48

__global__ void __launch_bounds__(1024) topk_kernel(const uint32_t* __restrict__ bcnt,
                                                    const unsigned long long* __restrict__ bcand,
                                                    float* __restrict__ boxes_out,
                                                    float* __restrict__ valid_out,
                                                    int4* __restrict__ sel,
                                                    uint32_t* __restrict__ order_out) {
    __shared__ uint32_t hist[NBUCK];
    __shared__ uint32_t scnts[BLKS_PER_IMG];
    __shared__ unsigned long long skeys[SELCAP];
    __shared__ uint32_t cell_by_rank[TOPK];
    __shared__ uint32_t sT, scnt;
    int b = blockIdx.x, t = threadIdx.x;

    if (t < NBUCK) hist[t] = 0;
    if (t < BLKS_PER_IMG) scnts[t] = bcnt[b * BLKS_PER_IMG + t];
    if (t == 0) { sT = 0; scnt = 0; }
    __syncthreads();

    const unsigned long long* cb = bcand + (size_t)b * BLKS_PER_IMG * SLOTS;

    // 1) histogram of value bits: bucket = (vb-LO)>>12, ~205 live buckets
    for (int s = t; s < BLKS_PER_IMG * SLOTS; s += 1024) {
        int j = s >> 8, i = s & (SLOTS - 1);
        if ((uint32_t)i < scnts[j]) {
            uint32_t vb = (uint32_t)(cb[(size_t)j * SLOTS + i] >> 32);
            uint32_t bk = (vb - VB_LO) >> BSHIFT;
            if (bk > (NBUCK - 1u)) bk = NBUCK - 1u;
            atomicAdd(&hist[bk], 1u);
        }
    }
    __syncthreads();

    // 2) inclusive suffix sum over NBUCK buckets
    for (int off = 1; off < NBUCK; off <<= 1) {
        uint32_t v = 0;
        if (t < NBUCK) v = hist[t] + ((t + off < NBUCK) ? hist[t + off] : 0u);
        __syncthreads();
        if (t < NBUCK) hist[t] = v;
        __syncthreads();
    }
    // T = max bucket with suffix count >= TOPK (0 if total < TOPK)
    if (t < NBUCK) {
        uint32_t st  = hist[t];
        uint32_t stn = (t < NBUCK - 1) ? hist[t + 1] : 0u;
        if (st >= TOPK && stn < TOPK) sT = (uint32_t)t;
    }
    __syncthreads();
    uint32_t T = sT;

    // 3) compact keys with bucket >= T into LDS
    for (int s = t; s < BLKS_PER_IMG * SLOTS; s += 1024) {
        int j = s >> 8, i = s & (SLOTS - 1);
        if ((uint32_t)i < scnts[j]) {
            unsigned long long key = cb[(size_t)j * SLOTS + i];
            uint32_t vb = (uint32_t)(key >> 32);
            uint32_t bk = (vb - VB_LO) >> BSHIFT;
            if (bk > (NBUCK - 1u)) bk = NBUCK - 1u;
            if (bk >= T) {
                uint32_t p = atomicAdd(&scnt, 1u);
                if (p < SELCAP) skeys[p] = key;
            }
        }
    }
    __syncthreads();
    int nsel = (int)min(scnt, (uint32_t)SELCAP);

    // prefill (only if fewer than TOPK peaks exist — not this input)
    if (nsel < TOPK && t < TOPK) {
        emit_entry(b, t, t, 0, boxes_out, valid_out, sel);
        cell_by_rank[t] = (uint32_t)t;
    }
    __syncthreads();

    // 4) rank by counting (keys unique -> ranks form a permutation); LDS broadcast reads
    for (int p = t; p < nsel; p += 1024) {
        unsigned long long key = skeys[p];
        int rank = 0;
        for (int i = 0; i < nsel; ++i)
            rank += (skeys[i] > key) ? 1 : 0;
        if (rank < TOPK) {
            int idx = (int)(~(uint32_t)key);
            emit_entry(b, rank, idx, 1, boxes_out, valid_out, sel);
            cell_by_rank[rank] = (uint32_t)idx;
        }
    }
    __syncthreads();

    // 5) spatial permutation: sort winners by (y,x,c) via rank-by-count (cells unique).
    if (t < TOPK) {
        uint32_t cell = cell_by_rank[t];
        uint32_t sk = ((cell & 0xFFFFu) << 2) | (cell >> 16);   // (y,x) major, c minor
        int sr = 0;
        for (int i = 0; i < TOPK; ++i) {
            uint32_t ci = cell_by_rank[i];
            uint32_t si = ((ci & 0xFFFFu) << 2) | (ci >> 16);
            sr += (si < sk) ? 1 : 0;
        }
        order_out[b * TOPK + sr] = (uint32_t)t;
    }
}

// ---------------- Kernel 3: ROI crop + 2x2/stride-1 maxpool, direct reads, no barriers ----
// 6144 blocks: bid&7 = image (XCD-pinned under round-robin), c outer, spatial slot inner.
// Thread t owns 4 consecutive output rows x 4 cols: direct per-thread loads of 5 image
// rows (vertical reuse in registers), no LDS, no __syncthreads -> no convoy; spatial
// ordering makes the 2x-amplified reads L2 hits. NT full-line stores keep L2 for reads.
__global__ void __launch_bounds__(256) crop_kernel(const float* __restrict__ images,
                                                   const int4* __restrict__ sel,
                                                   const uint32_t* __restrict__ order,
                                                   float* __restrict__ pooled) {
    int bid  = blockIdx.x;
    int b    = bid & 7;             // image = XCD under %8 round-robin (perf-only assumption)
    int r0   = bid >> 3;            // 0..767
    int c    = r0 >> 8;             // channel 0..2 (outer: one plane streamed at a time)
    int slot = r0 & 255;            // spatial slot 0..255
    int rank = (int)order[b * TOPK + slot];
    int bk   = b * TOPK + rank;
    int4 s = sel[bk];
    int y1 = s.x, x1 = s.y, vld = s.z;

    int t  = threadIdx.x;
    int j0 = (t & 15) * 4;          // output col start (0,4,..,60)
    int rb = t >> 4;                // row group 0..15 -> rows 4rb..4rb+3
    int xa = x1 & ~3;               // 16B-aligned floor (works for negatives)
    int c0 = x1 & 3;                // block-uniform window shift
    const float* img  = images + ((size_t)b * NC + c) * (size_t)(IMG * IMG);
    float*       outc = pooled + ((size_t)bk * NC + c) * 4096;

    int yt = y1 + rb * 4;           // top image row needed by this thread
    float Y[5][8];                  // rows yt..yt+4, cols xa+j0 .. +7
    bool fast = (x1 >= 0 && yt >= 0);   // max row = 287 < 1024; col max 287 < 1024
    if (fast) {
        const float* p0 = img + (size_t)yt * IMG + (xa + j0);
#pragma unroll
        for (int i = 0; i < 5; ++i) {
            f32x4 lo = *(const f32x4*)(p0 + (size_t)i * IMG);
            f32x4 hi = *(const f32x4*)(p0 + (size_t)i * IMG + 4);
#pragma unroll
            for (int e = 0; e < 4; ++e) { Y[i][e] = lo[e]; Y[i][e + 4] = hi[e]; }
        }
    } else {
#pragma unroll
        for (int i = 0; i < 5; ++i) {
            int yy = yt + i;
            const float* row = img + (size_t)yy * IMG;
            bool yv = (yy >= 0);
#pragma unroll
            for (int k = 0; k < 8; ++k) {
                int xx = xa + j0 + k;
                Y[i][k] = (yv && xx >= 0) ? row[xx] : NEGV;
            }
        }
    }

#pragma unroll
    for (int it = 0; it < 4; ++it) {
        float w[8];
#pragma unroll
        for (int k = 0; k < 8; ++k) w[k] = fmaxf(Y[it][k], Y[it + 1][k]);
        f32x4 o;
#define DO_C0(C0) { _Pragma("unroll") for (int e = 0; e < 4; ++e) o[e] = fmaxf(w[(C0) + e], w[(C0) + e + 1]); }
        switch (c0) {               // block-uniform -> scalar branch, all indices static
            case 0: DO_C0(0); break;
            case 1: DO_C0(1); break;
            case 2: DO_C0(2); break;
            default: DO_C0(3); break;
        }
#undef DO_C0
#pragma unroll
        for (int e = 0; e < 4; ++e) {
            float rr = o[e];
            if (!fast) rr = (rr < NEGV * 0.5f) ? 0.0f : rr;   // empty/outside bins -> 0
            if (!vld) rr = 0.0f;
            o[e] = rr;
        }
        __builtin_nontemporal_store(o, (f32x4*)(outc + (rb * 4 + it) * 64 + j0));
    }
}

extern "C" void kernel_launch(void* const* d_in, const int* in_sizes, int n_in,
                              void* d_out, int out_size, void* d_ws, size_t ws_size,
                              hipStream_t stream) {
    const float* grids  = (const float*)d_in[0];   // [8,3,256,256]
    const float* images = (const float*)d_in[1];   // [8,3,1024,1024]

    float* out = (float*)d_out;
    float* peaks_out = out;                                     // 8*3*256*256 = 1572864
    float* boxes_out = out + (size_t)NB * NC * HG * WG;         // 8*256*4     = 8192
    float* pooled_out = boxes_out + (size_t)NB * TOPK * 4;      // 8*256*3*64*64
    float* valid_out = pooled_out + (size_t)NB * TOPK * NC * 64 * 64;  // 8*256

    uint32_t* bcnt = (uint32_t*)d_ws;
    unsigned long long* bcand = (unsigned long long*)((char*)d_ws + WS_BCAND_OFF);
    int4* sel = (int4*)((char*)d_ws + WS_SEL_OFF);
    uint32_t* order = (uint32_t*)((char*)d_ws + WS_ORD_OFF);

    peaks_kernel<<<PK_BLOCKS, 256, 0, stream>>>(grids, peaks_out, bcnt, bcand);

    topk_kernel<<<NB, 1024, 0, stream>>>(bcnt, bcand, boxes_out, valid_out, sel, order);

    crop_kernel<<<NB * TOPK * NC, 256, 0, stream>>>(images, sel, order, pooled_out);
}

// Round 15
// 51.376 us; speedup vs baseline: 1.0501x; 1.0501x over previous
//
#include <hip/hip_runtime.h>
#include <stdint.h>
#include <math.h>

#define NB 8
#define NC 3
#define HG 256
#define WG 256
#define IMG 1024
#define TOPK 256
#define HALF 32
#define PEAK_THRESH 0.95f
#define NEGV (-1e30f)
#define SELCAP 2048        // selected-set capacity (expected nsel ~290)
#define VB_LO 0x3F733334u  // smallest float bits > 0.95f
// value range (0.95,1) spans 0xCCCCC = 838,860 ULPs; >>12 -> ~205 live buckets of 256
#define NBUCK 256
#define BSHIFT 12

#define ROWS_PB 16                 // rows per peaks block
#define GRPS (HG / ROWS_PB)        // 16 row-groups per plane
#define PLANES (NB * NC)           // 24
#define PK_BLOCKS (PLANES * GRPS)  // 384
#define SLOTS 256                  // candidate slots per peaks block (mean ~118)

// crop LDS patch: 65 rows x 68 cols staged, stride padded to 76 floats
#define PROWS 65
#define PQUADS 17                  // 17 f32x4 per row = 68 cols
#define PSTRIDE 76

typedef float f32x4 __attribute__((ext_vector_type(4)));

// ws layout (bytes):
//   [0, 1536)                      : uint32 bcnt[PK_BLOCKS]
//   [4096, 4096+PK_BLOCKS*SLOTS*8) : uint64 bcand[PK_BLOCKS][SLOTS]   (786 KB)
//   then                           : int4 sel[NB*TOPK]   {y1, x1, valid, 0}
//   then                           : uint32 order[NB*TOPK] (spatial slot -> value rank)
#define WS_BCAND_OFF 4096
#define WS_SEL_OFF   (WS_BCAND_OFF + (size_t)PK_BLOCKS * SLOTS * 8)
#define WS_ORD_OFF   (WS_SEL_OFF + (size_t)NB * TOPK * 16)

// ---------------- Kernel 1: 16-row-tile separable 5x5 peak NMS, slot compaction ----------------
__global__ void __launch_bounds__(256) peaks_kernel(const float* __restrict__ g,
                                                    float* __restrict__ peaks_out,
                                                    uint32_t* __restrict__ bcnt,
                                                    unsigned long long* __restrict__ bcand) {
    __shared__ float vms[ROWS_PB][WG];
    __shared__ unsigned long long lkeys[SLOTS];
    __shared__ uint32_t lcount;

    int blk   = blockIdx.x;
    int grp   = blk & (GRPS - 1);
    int plane = blk >> 4;              // b*NC + c
    int c     = plane % NC;
    int y0    = grp * ROWS_PB;
    int x     = threadIdx.x;

    if (x == 0) lcount = 0;

    const float* gc = g + (size_t)plane * (HG * WG);
    float col[ROWS_PB + 4];
#pragma unroll
    for (int d = 0; d < ROWS_PB + 4; ++d) {
        int yy = y0 - 2 + d;
        col[d] = (yy >= 0 && yy < HG) ? gc[yy * WG + x] : -INFINITY;
    }
#pragma unroll
    for (int r = 0; r < ROWS_PB; ++r)
        vms[r][x] = fmaxf(fmaxf(fmaxf(col[r], col[r + 1]), fmaxf(col[r + 2], col[r + 3])),
                          col[r + 4]);
    __syncthreads();                   // also orders lcount=0 before LDS atomics

#pragma unroll
    for (int r = 0; r < ROWS_PB; ++r) {
        float v = col[r + 2];
        float h = vms[r][x];
        if (x >= 2)      h = fmaxf(h, vms[r][x - 2]);
        if (x >= 1)      h = fmaxf(h, vms[r][x - 1]);
        if (x <= WG - 2) h = fmaxf(h, vms[r][x + 1]);
        if (x <= WG - 3) h = fmaxf(h, vms[r][x + 2]);
        bool peak = (h == v) && (v > PEAK_THRESH);
        peaks_out[(size_t)plane * (HG * WG) + (y0 + r) * WG + x] = peak ? v : 0.0f;
        if (peak) {
            uint32_t pos = atomicAdd(&lcount, 1u);
            if (pos < SLOTS) {
                int cell = c * (HG * WG) + (y0 + r) * WG + x;
                lkeys[pos] = ((unsigned long long)__float_as_uint(v) << 32) |
                             (uint32_t)(~(uint32_t)cell);
            }
        }
    }
    __syncthreads();
    uint32_t n = min(lcount, (uint32_t)SLOTS);
    if (x == 0) bcnt[blk] = n;
    if ((uint32_t)x < n) bcand[(size_t)blk * SLOTS + x] = lkeys[x];
}

// ---------------- Kernel 2: histogram-select + rank-by-count top-256 + spatial order ----------------
__device__ __forceinline__ void emit_entry(int b, int kk, int idx, int vld,
                                           float* boxes_out, float* valid_out, int4* sel) {
    int rem = idx & 65535;
    int cy = rem >> 8, cx = rem & 255;
    int x1 = cx - HALF, y1 = cy - HALF;
    float4 bo = make_float4((float)x1, (float)y1, (float)(cx + HALF), (float)(cy + HALF));
    *(float4*)(boxes_out + ((size_t)b * TOPK + kk) * 4) = bo;
    valid_out[b * TOPK + kk] = vld ? 1.0f : 0.0f;
    sel[b * TOPK + kk] = make_int4(y1, x1, vld, 0);
}

#define BLKS_PER_IMG (NC * GRPS)   // 48

__global__ void __launch_bounds__(1024) topk_kernel(const uint32_t* __restrict__ bcnt,
                                                    const unsigned long long* __restrict__ bcand,
                                                    float* __restrict__ boxes_out,
                                                    float* __restrict__ valid_out,
                                                    int4* __restrict__ sel,
                                                    uint32_t* __restrict__ order_out) {
    __shared__ uint32_t hist[NBUCK];
    __shared__ uint32_t scnts[BLKS_PER_IMG];
    __shared__ unsigned long long skeys[SELCAP];
    __shared__ uint32_t cell_by_rank[TOPK];
    __shared__ uint32_t sT, scnt;
    int b = blockIdx.x, t = threadIdx.x;

    if (t < NBUCK) hist[t] = 0;
    if (t < BLKS_PER_IMG) scnts[t] = bcnt[b * BLKS_PER_IMG + t];
    if (t == 0) { sT = 0; scnt = 0; }
    __syncthreads();

    const unsigned long long* cb = bcand + (size_t)b * BLKS_PER_IMG * SLOTS;

    // 1) histogram of value bits: bucket = (vb-LO)>>12, ~205 live buckets
    for (int s = t; s < BLKS_PER_IMG * SLOTS; s += 1024) {
        int j = s >> 8, i = s & (SLOTS - 1);
        if ((uint32_t)i < scnts[j]) {
            uint32_t vb = (uint32_t)(cb[(size_t)j * SLOTS + i] >> 32);
            uint32_t bk = (vb - VB_LO) >> BSHIFT;
            if (bk > (NBUCK - 1u)) bk = NBUCK - 1u;
            atomicAdd(&hist[bk], 1u);
        }
    }
    __syncthreads();

    // 2) inclusive suffix sum over NBUCK buckets
    for (int off = 1; off < NBUCK; off <<= 1) {
        uint32_t v = 0;
        if (t < NBUCK) v = hist[t] + ((t + off < NBUCK) ? hist[t + off] : 0u);
        __syncthreads();
        if (t < NBUCK) hist[t] = v;
        __syncthreads();
    }
    // T = max bucket with suffix count >= TOPK (0 if total < TOPK)
    if (t < NBUCK) {
        uint32_t st  = hist[t];
        uint32_t stn = (t < NBUCK - 1) ? hist[t + 1] : 0u;
        if (st >= TOPK && stn < TOPK) sT = (uint32_t)t;
    }
    __syncthreads();
    uint32_t T = sT;

    // 3) compact keys with bucket >= T into LDS
    for (int s = t; s < BLKS_PER_IMG * SLOTS; s += 1024) {
        int j = s >> 8, i = s & (SLOTS - 1);
        if ((uint32_t)i < scnts[j]) {
            unsigned long long key = cb[(size_t)j * SLOTS + i];
            uint32_t vb = (uint32_t)(key >> 32);
            uint32_t bk = (vb - VB_LO) >> BSHIFT;
            if (bk > (NBUCK - 1u)) bk = NBUCK - 1u;
            if (bk >= T) {
                uint32_t p = atomicAdd(&scnt, 1u);
                if (p < SELCAP) skeys[p] = key;
            }
        }
    }
    __syncthreads();
    int nsel = (int)min(scnt, (uint32_t)SELCAP);

    // prefill (only if fewer than TOPK peaks exist — not this input)
    if (nsel < TOPK && t < TOPK) {
        emit_entry(b, t, t, 0, boxes_out, valid_out, sel);
        cell_by_rank[t] = (uint32_t)t;
    }
    __syncthreads();

    // 4) rank by counting (keys unique -> ranks form a permutation); LDS broadcast reads
    for (int p = t; p < nsel; p += 1024) {
        unsigned long long key = skeys[p];
        int rank = 0;
        for (int i = 0; i < nsel; ++i)
            rank += (skeys[i] > key) ? 1 : 0;
        if (rank < TOPK) {
            int idx = (int)(~(uint32_t)key);
            emit_entry(b, rank, idx, 1, boxes_out, valid_out, sel);
            cell_by_rank[rank] = (uint32_t)idx;
        }
    }
    __syncthreads();

    // 5) spatial permutation: sort winners by (y,x,c) via rank-by-count (cells unique).
    if (t < TOPK) {
        uint32_t cell = cell_by_rank[t];
        uint32_t sk = ((cell & 0xFFFFu) << 2) | (cell >> 16);   // (y,x) major, c minor
        int sr = 0;
        for (int i = 0; i < TOPK; ++i) {
            uint32_t ci = cell_by_rank[i];
            uint32_t si = ((ci & 0xFFFFu) << 2) | (ci >> 16);
            sr += (si < sk) ? 1 : 0;
        }
        order_out[b * TOPK + sr] = (uint32_t)t;
    }
}

// ---------------- Kernel 3: ROI crop + 2x2/stride-1 maxpool via LDS-staged patch ----------------
// Channel-split: 6144 blocks, one (image, channel, spatial-slot) patch each.
// bid&7 = image (XCD-pinned under round-robin dispatch); c outer, slot inner so 256
// consecutive blocks per image stream ONE plane in spatial order (L2 row reuse).
// LDS staging reads each patch byte exactly once (R10/R14 A/B: worth ~2 us vs direct).
// NT full-line stores (lane-contiguous 1KB/wave-instr) keep the write stream out of L2.
__global__ void __launch_bounds__(256) crop_kernel(const float* __restrict__ images,
                                                   const int4* __restrict__ sel,
                                                   const uint32_t* __restrict__ order,
                                                   float* __restrict__ pooled) {
    __shared__ float patch[PROWS * PSTRIDE];   // 65*76*4B = 19.76 KB

    int bid  = blockIdx.x;
    int b    = bid & 7;             // image = XCD under %8 round-robin (perf-only assumption)
    int r0   = bid >> 3;            // 0..767
    int c    = r0 >> 8;             // channel 0..2 (outer: one plane streamed at a time)
    int slot = r0 & 255;            // spatial slot 0..255
    int rank = (int)order[b * TOPK + slot];
    int bk   = b * TOPK + rank;
    int4 s = sel[bk];
    int y1 = s.x, x1 = s.y, vld = s.z;

    int t  = threadIdx.x;
    int j0 = (t & 15) * 4;          // output col start (0,4,..,60)
    int rb = t >> 4;                // row group 0..15 -> rows 4rb..4rb+3
    int xa = x1 & ~3;               // 16B-aligned floor (works for negatives)
    int c0 = x1 & 3;                // block-uniform window shift
    bool fast = (x1 >= 0 && y1 >= 0);   // whole patch in-image (max row/col 287 < 1024)

    const float* img  = images + ((size_t)b * NC + c) * (size_t)(IMG * IMG);
    float*       outc = pooled + ((size_t)bk * NC + c) * 4096;

    // ---- stage patch rows y1..y1+64, cols xa..xa+67 (exactly once per (bk,c)) ----
    if (fast) {
        const float* p0 = img + (size_t)y1 * IMG + xa;
        for (int i = t; i < PROWS * PQUADS; i += 256) {
            int row = i / PQUADS, q = i - row * PQUADS;
            f32x4 v = *(const f32x4*)(p0 + (size_t)row * IMG + q * 4);
            *(f32x4*)(&patch[row * PSTRIDE + q * 4]) = v;
        }
    } else {
        for (int i = t; i < PROWS * PQUADS; i += 256) {
            int row = i / PQUADS, q = i - row * PQUADS;
            int yy = y1 + row;
            const float* rowp = img + (size_t)yy * IMG;
            f32x4 v;
#pragma unroll
            for (int e = 0; e < 4; ++e) {
                int xx = xa + q * 4 + e;
                v[e] = (yy >= 0 && xx >= 0) ? rowp[xx] : NEGV;
            }
            *(f32x4*)(&patch[row * PSTRIDE + q * 4]) = v;
        }
    }
    __syncthreads();

    // ---- compute 4 rows x 4 cols per thread from LDS (vertical reuse) ----
    float Y[5][8];
#pragma unroll
    for (int i = 0; i < 5; ++i) {
        f32x4 lo = *(const f32x4*)(&patch[(rb * 4 + i) * PSTRIDE + j0]);
        f32x4 hi = *(const f32x4*)(&patch[(rb * 4 + i) * PSTRIDE + j0 + 4]);
#pragma unroll
        for (int e = 0; e < 4; ++e) { Y[i][e] = lo[e]; Y[i][e + 4] = hi[e]; }
    }
#pragma unroll
    for (int it = 0; it < 4; ++it) {
        float w[8];
#pragma unroll
        for (int k = 0; k < 8; ++k) w[k] = fmaxf(Y[it][k], Y[it + 1][k]);
        f32x4 o;
#define DO_C0(C0) { _Pragma("unroll") for (int e = 0; e < 4; ++e) o[e] = fmaxf(w[(C0) + e], w[(C0) + e + 1]); }
        switch (c0) {               // block-uniform -> scalar branch, all indices static
            case 0: DO_C0(0); break;
            case 1: DO_C0(1); break;
            case 2: DO_C0(2); break;
            default: DO_C0(3); break;
        }
#undef DO_C0
#pragma unroll
        for (int e = 0; e < 4; ++e) {
            float rr = o[e];
            if (!fast) rr = (rr < NEGV * 0.5f) ? 0.0f : rr;   // empty/outside bins -> 0
            if (!vld) rr = 0.0f;
            o[e] = rr;
        }
        __builtin_nontemporal_store(o, (f32x4*)(outc + (rb * 4 + it) * 64 + j0));
    }
}

extern "C" void kernel_launch(void* const* d_in, const int* in_sizes, int n_in,
                              void* d_out, int out_size, void* d_ws, size_t ws_size,
                              hipStream_t stream) {
    const float* grids  = (const float*)d_in[0];   // [8,3,256,256]
    const float* images = (const float*)d_in[1];   // [8,3,1024,1024]

    float* out = (float*)d_out;
    float* peaks_out = out;                                     // 8*3*256*256 = 1572864
    float* boxes_out = out + (size_t)NB * NC * HG * WG;         // 8*256*4     = 8192
    float* pooled_out = boxes_out + (size_t)NB * TOPK * 4;      // 8*256*3*64*64
    float* valid_out = pooled_out + (size_t)NB * TOPK * NC * 64 * 64;  // 8*256

    uint32_t* bcnt = (uint32_t*)d_ws;
    unsigned long long* bcand = (unsigned long long*)((char*)d_ws + WS_BCAND_OFF);
    int4* sel = (int4*)((char*)d_ws + WS_SEL_OFF);
    uint32_t* order = (uint32_t*)((char*)d_ws + WS_ORD_OFF);

    peaks_kernel<<<PK_BLOCKS, 256, 0, stream>>>(grids, peaks_out, bcnt, bcand);

    topk_kernel<<<NB, 1024, 0, stream>>>(bcnt, bcand, boxes_out, valid_out, sel, order);

    crop_kernel<<<NB * TOPK * NC, 256, 0, stream>>>(images, sel, order, pooled_out);
}